// Round 5
// baseline (127.800 us; speedup 1.0000x reference)
//
#include <hip/hip_runtime.h>
#include <hip/hip_bf16.h>

// QuantizedConv2d: N=32, CIN=128, H=W=56, COUT=256, 3x3, pad=1 (zp=-3), stride 1.
// Implicit GEMM with mfma_i32_16x16x64_i8.
// Round 4: PADDED NHWC input [32][58][58][128] with zp baked in -> all conv
// loads unconditional (compiler can hoist/pipeline); revert nontemporal stores
// (measured net-negative: WRITE 103->133 MB).

typedef __attribute__((ext_vector_type(4))) int i32x4;

#define NB_N 32
#define CIN 128
#define HH 56
#define WW 56
#define PH 58                             // padded H/W
#define COUT 256
#define PIX_PER_IMG (HH*WW)               // 3136
#define X_IMG_INTS (PIX_PER_IMG*CIN)      // int32 elems per input image
#define TOTAL_PIX (NB_N*PIX_PER_IMG)      // 100352
#define XP_IMG_BYTES (PH*PH*CIN)          // 430592
#define XQ_PAD_BYTES ((size_t)NB_N*XP_IMG_BYTES)   // 13778944

// ---------------- pack_x: NCHW int32 -> padded NHWC int8 ----------------
// Writes interior row (h+1), cols 1..56 of the padded image; halos stay 0xFD
// from the memset.
__global__ __launch_bounds__(256) void pack_x_kernel(const int* __restrict__ x,
                                                     signed char* __restrict__ xq) {
    __shared__ signed char tile[WW * CIN];   // 7168 B, [w][c]
    int nh = blockIdx.x;                     // 0..N*H-1
    int n = nh / HH, h = nh - n * HH;
    const int* src = x + (size_t)n * X_IMG_INTS + h * WW;  // (n, c, h, 0)
    for (int t = threadIdx.x; t < WW * CIN; t += 256) {
        int c = t / WW;
        int w = t - c * WW;
        int v = src[c * PIX_PER_IMG + w];
        tile[w * CIN + c] = (signed char)v;
    }
    __syncthreads();
    int* dst = (int*)(xq + (size_t)n * XP_IMG_BYTES + ((size_t)(h + 1) * PH + 1) * CIN);
    const int* s4 = (const int*)tile;
    for (int t = threadIdx.x; t < (WW * CIN) / 4; t += 256)
        dst[t] = s4[t];
}

// ---------------- pack_w: OIHW int32 -> fragment-ordered int8 ----------------
// wq byte layout: frag f = (tap*2 + kb)*16 + nfrag, then lane*16 + j
// maps to weight[cout = nfrag*16 + (lane&15)][cin = kb*64 + (lane>>4)*16 + j][kh][kw]
__global__ __launch_bounds__(256) void pack_w_kernel(const int* __restrict__ w,
                                                     signed char* __restrict__ wq) {
    int idx = blockIdx.x * 256 + threadIdx.x;    // 0..18431
    if (idx >= 9 * 2 * 16 * 64) return;
    int lane = idx & 63;
    int fid = idx >> 6;            // 0..287
    int t = fid / 32;              // tap
    int rem = fid - t * 32;
    int kb = rem >> 4;
    int nf = rem & 15;
    int cout = nf * 16 + (lane & 15);
    int cinb = kb * 64 + (lane >> 4) * 16;
    int kh = t / 3, kw = t - kh * 3;
    union { signed char b[16]; i32x4 v; } u;
#pragma unroll
    for (int j = 0; j < 16; ++j) {
        int cin = cinb + j;
        u.b[j] = (signed char)w[((cout * CIN + cin) * 3 + kh) * 3 + kw];
    }
    *(i32x4*)(wq + (size_t)idx * 16) = u.v;
}

// ---------------- conv: implicit GEMM, 16x16x64 i8 MFMA ----------------
// grid = (TOTAL_PIX/256) * 4 blocks of 256 threads.
// block: mt = bid>>2 (256 pixels), nb = bid&3 (64 couts).
// wave wv owns 64 consecutive pixels (4 M-frags) x 64 couts (4 N-frags).
__global__ __launch_bounds__(256, 3) void conv_kernel(const signed char* __restrict__ xq,
                                                      const signed char* __restrict__ wq,
                                                      const int* __restrict__ bias,
                                                      const float* __restrict__ wscale,
                                                      int* __restrict__ out) {
    int bid = blockIdx.x;
    int mt = bid >> 2;
    int nb = bid & 3;
    int lane = threadIdx.x & 63;
    int wv = threadIdx.x >> 6;
    int pbase = mt * 256 + wv * 64;
    int row = lane & 15;
    int grp = lane >> 4;

    int p0 = pbase + row;
    int n = p0 / PIX_PER_IMG;
    int local0 = p0 - n * PIX_PER_IMG;

    // Per-m base pointer into the PADDED image at (h+1, w+1), +grp*16.
    const signed char* pm[4];
#pragma unroll
    for (int m = 0; m < 4; ++m) {
        int rm = local0 + m * 16;
        int hm = rm / WW;
        int wm = rm - hm * WW;
        pm[m] = xq + (size_t)n * XP_IMG_BYTES
                   + ((size_t)(hm + 1) * PH + (wm + 1)) * CIN + grp * 16;
    }

    i32x4 acc[4][4] = {};

#pragma unroll
    for (int t = 0; t < 9; ++t) {
        const int dh = t / 3 - 1, dw = t % 3 - 1;
        const int toff = (dh * PH + dw) * CIN;    // compile-time per-tap byte offset
        const signed char* wb = wq + ((size_t)((t * 2) * 16 + nb * 4)) * 1024 + lane * 16;
#pragma unroll
        for (int kb = 0; kb < 2; ++kb) {
            i32x4 a[4], b[4];
#pragma unroll
            for (int m = 0; m < 4; ++m)
                a[m] = *(const i32x4*)(pm[m] + toff + kb * 64);
#pragma unroll
            for (int j = 0; j < 4; ++j)
                b[j] = *(const i32x4*)(wb + (size_t)(kb * 16 + j) * 1024);
#pragma unroll
            for (int m = 0; m < 4; ++m)
#pragma unroll
                for (int j = 0; j < 4; ++j)
                    acc[m][j] = __builtin_amdgcn_mfma_i32_16x16x64_i8(a[m], b[j], acc[m][j], 0, 0, 0);
        }
    }

    // Epilogue: out_i = acc + 2*bias; f = out_i * (0.05*ws/0.1) + 5; rint; clamp; int32 store.
    // C/D frag: col (cout) = lane&15, row (pixel) = grp*4 + reg.
    float sc[4];
    int b2[4];
#pragma unroll
    for (int j = 0; j < 4; ++j) {
        int cout = nb * 64 + j * 16 + row;
        sc[j] = wscale[cout] * 0.5f;          // 0.05/0.1 * ws
        b2[j] = 2 * bias[cout];
    }
#pragma unroll
    for (int m = 0; m < 4; ++m) {
        int pix = pbase + m * 16 + grp * 4;          // pixel of reg 0
        int local = pix - n * PIX_PER_IMG;           // h*56 + w
        size_t obase = (size_t)n * (COUT * PIX_PER_IMG) + local;
#pragma unroll
        for (int j = 0; j < 4; ++j) {
            int cout = nb * 64 + j * 16 + row;
            i32x4 v;
#pragma unroll
            for (int r = 0; r < 4; ++r) {
                int o = acc[m][j][r] + b2[j];
                float f = fmaf((float)o, sc[j], 5.0f);
                f = rintf(f);                         // RNE == jnp.round
                f = fminf(fmaxf(f, -128.0f), 127.0f);
                v[r] = (int)f;
            }
            *(i32x4*)(out + obase + (size_t)cout * PIX_PER_IMG) = v;
        }
    }
}

extern "C" void kernel_launch(void* const* d_in, const int* in_sizes, int n_in,
                              void* d_out, int out_size, void* d_ws, size_t ws_size,
                              hipStream_t stream) {
    const int* x = (const int*)d_in[0];
    const int* w = (const int*)d_in[1];
    const int* bias = (const int*)d_in[2];
    const float* ws = (const float*)d_in[3];
    int* out = (int*)d_out;

    signed char* xq = (signed char*)d_ws;                 // padded NHWC int8
    signed char* wq = xq + XQ_PAD_BYTES;                  // 288 KB fragment-ordered weights

    hipMemsetAsync(xq, 0xFD, XQ_PAD_BYTES, stream);       // bake zp=-3 halos
    pack_x_kernel<<<NB_N * HH, 256, 0, stream>>>(x, xq);
    pack_w_kernel<<<72, 256, 0, stream>>>(w, wq);
    conv_kernel<<<(TOTAL_PIX / 256) * 4, 256, 0, stream>>>(xq, wq, bias, ws, out);
}

// Round 6
// 86.059 us; speedup vs baseline: 1.4850x; 1.4850x over previous
//
#include <hip/hip_runtime.h>

// QuantizedConv2d: N=32, CIN=128, H=W=56, COUT=256, 3x3, pad=1 (zp=-3), stride 1.
// Round 5: LDS-staged implicit GEMM (mfma_i32_16x16x64_i8).
//   Block 256thr = 2x2 waves, tile 224px(4 rows) x 128 couts, 18 K-steps.
//   A: 6 padded rows (43.5KB) staged ONCE in LDS, XOR-swizzled (T2) -> conflict-free.
//   B: 8KB/step double-buffered, reg-staged (T14: load early, ds_write after MFMA).
//   XCD-chunked swizzle: 112 consecutive blocks (4 images) per XCD.

typedef __attribute__((ext_vector_type(4))) int i32x4;

#define NB_N 32
#define CIN 128
#define HH 56
#define WW 56
#define PH 58                              // padded H/W
#define COUT 256
#define PIX_PER_IMG (HH*WW)                // 3136
#define X_IMG_INTS (PIX_PER_IMG*CIN)
#define XP_ROW_BYTES (PH*CIN)              // 7424
#define XP_IMG_BYTES (PH*XP_ROW_BYTES)     // 430592
#define XQ_PAD_BYTES ((size_t)NB_N*XP_IMG_BYTES)
#define A_BYTES (6*XP_ROW_BYTES)           // 44544
#define B_STEP 8192

// ---------------- pack_x: NCHW int32 -> padded NHWC int8 ----------------
__global__ __launch_bounds__(256) void pack_x_kernel(const int* __restrict__ x,
                                                     signed char* __restrict__ xq) {
    __shared__ signed char tile[WW * CIN];   // [w][c]
    int nh = blockIdx.x;                     // 0..N*H-1
    int n = nh / HH, h = nh - n * HH;
    const int* src = x + (size_t)n * X_IMG_INTS + h * WW;  // (n, c, h, 0)
    for (int t = threadIdx.x; t < WW * CIN; t += 256) {
        int c = t / WW;
        int w = t - c * WW;
        int v = src[c * PIX_PER_IMG + w];
        tile[w * CIN + c] = (signed char)v;
    }
    __syncthreads();
    int* dst = (int*)(xq + (size_t)n * XP_IMG_BYTES + ((size_t)(h + 1) * PH + 1) * CIN);
    const int* s4 = (const int*)tile;
    for (int t = threadIdx.x; t < (WW * CIN) / 4; t += 256)
        dst[t] = s4[t];
}

// ---------------- pack_w: OIHW int32 -> fragment-ordered int8 ----------------
// frag f = (tap*2 + kb)*16 + nfrag; byte = f*1024 + lane*16 + j
// -> weight[cout = nfrag*16 + (lane&15)][cin = kb*64 + (lane>>4)*16 + j][kh][kw]
__global__ __launch_bounds__(256) void pack_w_kernel(const int* __restrict__ w,
                                                     signed char* __restrict__ wq) {
    int idx = blockIdx.x * 256 + threadIdx.x;    // 0..18431
    if (idx >= 9 * 2 * 16 * 64) return;
    int lane = idx & 63;
    int fid = idx >> 6;
    int t = fid / 32;
    int rem = fid - t * 32;
    int kb = rem >> 4;
    int nf = rem & 15;
    int cout = nf * 16 + (lane & 15);
    int cinb = kb * 64 + (lane >> 4) * 16;
    int kh = t / 3, kw = t - kh * 3;
    union { signed char b[16]; i32x4 v; } u;
#pragma unroll
    for (int j = 0; j < 16; ++j) {
        int cin = cinb + j;
        u.b[j] = (signed char)w[((cout * CIN + cin) * 3 + kh) * 3 + kw];
    }
    *(i32x4*)(wq + (size_t)idx * 16) = u.v;
}

// ---------------- conv: LDS-staged implicit GEMM ----------------
// grid = 896 blocks: img n (32) x rowblk rb (14, 4 rows each) x coutblk cb (2, 128 couts).
// wave (pxhalf, chalf): 112 px (7 m-frags) x 64 couts (4 n-frags); acc[7][4].
__global__ __launch_bounds__(256, 2) void conv_kernel(const signed char* __restrict__ xq,
                                                      const signed char* __restrict__ wq,
                                                      const int* __restrict__ bias,
                                                      const float* __restrict__ wscale,
                                                      int* __restrict__ out) {
    __shared__ __align__(16) signed char lds[A_BYTES + 2 * B_STEP];
    const int tid = threadIdx.x;
    const int lane = tid & 63, wv = tid >> 6;
    const int row = lane & 15, grp = lane >> 4;

    // XCD-chunked swizzle: 896 = 8*112; consecutive 112 blocks (4 images) per XCD.
    int orig = (blockIdx.x & 7) * 112 + (blockIdx.x >> 3);
    int n = orig / 28;
    int rr = orig - n * 28;
    int rb = rr >> 1;          // row-block: output rows [rb*4, rb*4+4)
    int cb = rr & 1;           // cout half: [cb*128, +128)
    int pxhalf = wv >> 1, chalf = wv & 1;

    const signed char* ximg = xq + (size_t)n * XP_IMG_BYTES + (size_t)rb * 4 * XP_ROW_BYTES;

    // ---- prologue: A-halo (6 padded rows) into LDS, swizzled ----
    // LDS[d] = global[g],  g = d ^ (((d>>7)&7)<<4)   (involution on bits 4-6)
#pragma unroll
    for (int k = 0; k < 11; ++k) {
        int d = k * 4096 + tid * 16;
        if (d < A_BYTES) {
            int g = d ^ (((d >> 7) & 7) << 4);
            i32x4 v = *(const i32x4*)(ximg + g);
            *(i32x4*)(lds + d) = v;
        }
    }
    // stage B step 0 (frag base = (0*16 + cb*8)*1024)
    {
        const signed char* s0 = wq + (size_t)(cb * 8) * 1024 + tid * 16;
        i32x4 v0 = *(const i32x4*)(s0);
        i32x4 v1 = *(const i32x4*)(s0 + 4096);
        *(i32x4*)(lds + A_BYTES + tid * 16) = v0;
        *(i32x4*)(lds + A_BYTES + 4096 + tid * 16) = v1;
    }
    __syncthreads();

    // per-m center pixel index in halo (padded coords, rows 0..5 of halo)
    int pc[7];
#pragma unroll
    for (int m = 0; m < 7; ++m) {
        int off = pxhalf * 112 + m * 16 + row;               // 0..223
        int lr = (off >= 56) + (off >= 112) + (off >= 168);  // off/56
        int w = off - lr * 56;
        pc[m] = (lr + 1) * PH + (w + 1);
    }

    const int tapd[9] = {-PH - 1, -PH, -PH + 1, -1, 0, 1, PH - 1, PH, PH + 1};

    i32x4 acc[7][4] = {};
    i32x4 nb0, nb1;

#pragma unroll
    for (int s = 0; s < 18; ++s) {
        const int t = s >> 1, kb = s & 1;
        if (s < 17) {   // T14: issue next-step B loads early (latency hides under MFMAs)
            const signed char* src = wq + ((size_t)((s + 1) * 16 + cb * 8)) * 1024 + tid * 16;
            nb0 = *(const i32x4*)(src);
            nb1 = *(const i32x4*)(src + 4096);
        }
        // A ds_reads (swizzled)
        i32x4 a[7];
#pragma unroll
        for (int m = 0; m < 7; ++m) {
            int pix = pc[m] + tapd[t];
            int g = (pix << 7) + (kb << 6) + (grp << 4);
            int d = g ^ ((pix & 7) << 4);
            a[m] = *(const i32x4*)(lds + d);
        }
        // B ds_reads (contiguous, conflict-free)
        const signed char* bb = lds + A_BYTES + (s & 1) * B_STEP + (chalf * 4) * 1024 + lane * 16;
        i32x4 b[4];
#pragma unroll
        for (int j = 0; j < 4; ++j) b[j] = *(const i32x4*)(bb + (size_t)j * 1024);
#pragma unroll
        for (int m = 0; m < 7; ++m)
#pragma unroll
            for (int j = 0; j < 4; ++j)
                acc[m][j] = __builtin_amdgcn_mfma_i32_16x16x64_i8(a[m], b[j], acc[m][j], 0, 0, 0);
        if (s < 17) {   // write next-step B into the other buffer
            signed char* dst = lds + A_BYTES + ((s + 1) & 1) * B_STEP + tid * 16;
            *(i32x4*)(dst) = nb0;
            *(i32x4*)(dst + 4096) = nb1;
        }
        __syncthreads();
    }

    // ---- epilogue: acc + 2*bias -> scale -> rint -> clamp -> int32 store ----
    float sc[4];
    int b2[4];
    const int coutbase = cb * 128 + chalf * 64;
#pragma unroll
    for (int j = 0; j < 4; ++j) {
        int cout = coutbase + j * 16 + row;
        sc[j] = wscale[cout] * 0.5f;          // 0.05/0.1 * ws
        b2[j] = 2 * bias[cout];
    }
    const int pixbase = rb * 224 + pxhalf * 112;
#pragma unroll
    for (int m = 0; m < 7; ++m) {
        int pl = pixbase + m * 16 + grp * 4;  // pixel of reg 0
        size_t obase = (size_t)n * (COUT * PIX_PER_IMG) + pl;
#pragma unroll
        for (int j = 0; j < 4; ++j) {
            int cout = coutbase + j * 16 + row;
            i32x4 v;
#pragma unroll
            for (int r = 0; r < 4; ++r) {
                int o = acc[m][j][r] + b2[j];
                float f = fmaf((float)o, sc[j], 5.0f);
                f = rintf(f);                 // RNE == jnp.round
                f = fminf(fmaxf(f, -128.0f), 127.0f);
                v[r] = (int)f;
            }
            *(i32x4*)(out + obase + (size_t)cout * PIX_PER_IMG) = v;
        }
    }
}

extern "C" void kernel_launch(void* const* d_in, const int* in_sizes, int n_in,
                              void* d_out, int out_size, void* d_ws, size_t ws_size,
                              hipStream_t stream) {
    const int* x = (const int*)d_in[0];
    const int* w = (const int*)d_in[1];
    const int* bias = (const int*)d_in[2];
    const float* ws = (const float*)d_in[3];
    int* out = (int*)d_out;

    signed char* xq = (signed char*)d_ws;                 // padded NHWC int8
    signed char* wq = xq + XQ_PAD_BYTES;                  // 288 KB fragment-ordered weights

    hipMemsetAsync(xq, 0xFD, XQ_PAD_BYTES, stream);       // bake zp=-3 halos
    pack_x_kernel<<<NB_N * HH, 256, 0, stream>>>(x, xq);
    pack_w_kernel<<<72, 256, 0, stream>>>(w, wq);
    conv_kernel<<<896, 256, 0, stream>>>(xq, wq, bias, ws, out);
}

// Round 7
// 82.140 us; speedup vs baseline: 1.5559x; 1.0477x over previous
//
#include <hip/hip_runtime.h>

// QuantizedConv2d: N=32, CIN=128, H=W=56, COUT=256, 3x3, pad=1 (zp=-3), stride 1.
// Round 6: replace hipMemsetAsync(13.8MB, 59.6us measured!) with a tiny
// halo-fill kernel (0.93MB of actual halo bytes). Conv/pack unchanged from r5:
//   Block 256thr = 2x2 waves, tile 224px(4 rows) x 128 couts, 18 K-steps.
//   A: 6 padded rows (43.5KB) staged ONCE in LDS, XOR-swizzled -> conflict-free.
//   B: 8KB/step double-buffered, reg-staged (T14).
//   XCD-chunked swizzle: 112 consecutive blocks (4 images) per XCD.

typedef __attribute__((ext_vector_type(4))) int i32x4;

#define NB_N 32
#define CIN 128
#define HH 56
#define WW 56
#define PH 58                              // padded H/W
#define COUT 256
#define PIX_PER_IMG (HH*WW)                // 3136
#define X_IMG_INTS (PIX_PER_IMG*CIN)
#define XP_ROW_BYTES (PH*CIN)              // 7424
#define XP_IMG_BYTES (PH*XP_ROW_BYTES)     // 430592
#define XQ_PAD_BYTES ((size_t)NB_N*XP_IMG_BYTES)
#define A_BYTES (6*XP_ROW_BYTES)           // 44544
#define B_STEP 8192

// ---------------- halo: fill padded-image borders with zp (0xFD) ----------------
__global__ __launch_bounds__(256) void halo_kernel(signed char* __restrict__ xq) {
    const i32x4 pad = {(int)0xFDFDFDFD, (int)0xFDFDFDFD, (int)0xFDFDFDFD, (int)0xFDFDFDFD};
    signed char* img = xq + (size_t)blockIdx.x * XP_IMG_BYTES;
    // full rows 0 and 57: 7424 B each = 464 x 16B
    for (int t = threadIdx.x; t < 928; t += 256) {
        int r = (t < 464) ? 0 : 57;
        int off = ((t < 464) ? t : t - 464) * 16;
        *(i32x4*)(img + (size_t)r * XP_ROW_BYTES + off) = pad;
    }
    // side columns w=0,57 for rows 1..56: 112 pixels x 8 x 16B
    for (int t = threadIdx.x; t < 896; t += 256) {
        int px = t >> 3;                  // 0..111
        int q = t & 7;
        int r = 1 + (px >> 1);            // 1..56
        int w = (px & 1) ? 57 : 0;
        *(i32x4*)(img + ((size_t)r * PH + w) * CIN + q * 16) = pad;
    }
}

// ---------------- pack_x: NCHW int32 -> padded NHWC int8 ----------------
__global__ __launch_bounds__(256) void pack_x_kernel(const int* __restrict__ x,
                                                     signed char* __restrict__ xq) {
    __shared__ signed char tile[WW * CIN];   // [w][c]
    int nh = blockIdx.x;                     // 0..N*H-1
    int n = nh / HH, h = nh - n * HH;
    const int* src = x + (size_t)n * X_IMG_INTS + h * WW;  // (n, c, h, 0)
    for (int t = threadIdx.x; t < WW * CIN; t += 256) {
        int c = t / WW;
        int w = t - c * WW;
        int v = src[c * PIX_PER_IMG + w];
        tile[w * CIN + c] = (signed char)v;
    }
    __syncthreads();
    int* dst = (int*)(xq + (size_t)n * XP_IMG_BYTES + ((size_t)(h + 1) * PH + 1) * CIN);
    const int* s4 = (const int*)tile;
    for (int t = threadIdx.x; t < (WW * CIN) / 4; t += 256)
        dst[t] = s4[t];
}

// ---------------- pack_w: OIHW int32 -> fragment-ordered int8 ----------------
// frag f = (tap*2 + kb)*16 + nfrag; byte = f*1024 + lane*16 + j
// -> weight[cout = nf*16 + (lane&15)][cin = kb*64 + (lane>>4)*16 + j][kh][kw]
__global__ __launch_bounds__(256) void pack_w_kernel(const int* __restrict__ w,
                                                     signed char* __restrict__ wq) {
    int idx = blockIdx.x * 256 + threadIdx.x;    // 0..18431
    if (idx >= 9 * 2 * 16 * 64) return;
    int lane = idx & 63;
    int fid = idx >> 6;
    int t = fid / 32;
    int rem = fid - t * 32;
    int kb = rem >> 4;
    int nf = rem & 15;
    int cout = nf * 16 + (lane & 15);
    int cinb = kb * 64 + (lane >> 4) * 16;
    int kh = t / 3, kw = t - kh * 3;
    union { signed char b[16]; i32x4 v; } u;
#pragma unroll
    for (int j = 0; j < 16; ++j) {
        int cin = cinb + j;
        u.b[j] = (signed char)w[((cout * CIN + cin) * 3 + kh) * 3 + kw];
    }
    *(i32x4*)(wq + (size_t)idx * 16) = u.v;
}

// ---------------- conv: LDS-staged implicit GEMM ----------------
// grid = 896 blocks: img n (32) x rowblk rb (14, 4 rows each) x coutblk cb (2).
// wave (pxhalf, chalf): 112 px (7 m-frags) x 64 couts (4 n-frags); acc[7][4].
__global__ __launch_bounds__(256, 2) void conv_kernel(const signed char* __restrict__ xq,
                                                      const signed char* __restrict__ wq,
                                                      const int* __restrict__ bias,
                                                      const float* __restrict__ wscale,
                                                      int* __restrict__ out) {
    __shared__ __align__(16) signed char lds[A_BYTES + 2 * B_STEP];
    const int tid = threadIdx.x;
    const int lane = tid & 63, wv = tid >> 6;
    const int row = lane & 15, grp = lane >> 4;

    // XCD-chunked swizzle: 896 = 8*112; consecutive 112 blocks (4 images) per XCD.
    int orig = (blockIdx.x & 7) * 112 + (blockIdx.x >> 3);
    int n = orig / 28;
    int rr = orig - n * 28;
    int rb = rr >> 1;          // row-block: output rows [rb*4, rb*4+4)
    int cb = rr & 1;           // cout half: [cb*128, +128)
    int pxhalf = wv >> 1, chalf = wv & 1;

    const signed char* ximg = xq + (size_t)n * XP_IMG_BYTES + (size_t)rb * 4 * XP_ROW_BYTES;

    // ---- prologue: A-halo (6 padded rows) into LDS, swizzled ----
    // LDS[d] = global[g],  g = d ^ (((d>>7)&7)<<4)   (involution on bits 4-6)
#pragma unroll
    for (int k = 0; k < 11; ++k) {
        int d = k * 4096 + tid * 16;
        if (d < A_BYTES) {
            int g = d ^ (((d >> 7) & 7) << 4);
            i32x4 v = *(const i32x4*)(ximg + g);
            *(i32x4*)(lds + d) = v;
        }
    }
    // stage B step 0 (frag base = (0*16 + cb*8)*1024)
    {
        const signed char* s0 = wq + (size_t)(cb * 8) * 1024 + tid * 16;
        i32x4 v0 = *(const i32x4*)(s0);
        i32x4 v1 = *(const i32x4*)(s0 + 4096);
        *(i32x4*)(lds + A_BYTES + tid * 16) = v0;
        *(i32x4*)(lds + A_BYTES + 4096 + tid * 16) = v1;
    }
    __syncthreads();

    // per-m center pixel index in halo (padded coords, rows 0..5 of halo)
    int pc[7];
#pragma unroll
    for (int m = 0; m < 7; ++m) {
        int off = pxhalf * 112 + m * 16 + row;               // 0..223
        int lr = (off >= 56) + (off >= 112) + (off >= 168);  // off/56
        int w = off - lr * 56;
        pc[m] = (lr + 1) * PH + (w + 1);
    }

    const int tapd[9] = {-PH - 1, -PH, -PH + 1, -1, 0, 1, PH - 1, PH, PH + 1};

    i32x4 acc[7][4] = {};
    i32x4 nb0, nb1;

#pragma unroll
    for (int s = 0; s < 18; ++s) {
        const int t = s >> 1, kb = s & 1;
        if (s < 17) {   // T14: issue next-step B loads early (latency hides under MFMAs)
            const signed char* src = wq + ((size_t)((s + 1) * 16 + cb * 8)) * 1024 + tid * 16;
            nb0 = *(const i32x4*)(src);
            nb1 = *(const i32x4*)(src + 4096);
        }
        // A ds_reads (swizzled)
        i32x4 a[7];
#pragma unroll
        for (int m = 0; m < 7; ++m) {
            int pix = pc[m] + tapd[t];
            int g = (pix << 7) + (kb << 6) + (grp << 4);
            int d = g ^ ((pix & 7) << 4);
            a[m] = *(const i32x4*)(lds + d);
        }
        // B ds_reads (contiguous, conflict-free)
        const signed char* bb = lds + A_BYTES + (s & 1) * B_STEP + (chalf * 4) * 1024 + lane * 16;
        i32x4 b[4];
#pragma unroll
        for (int j = 0; j < 4; ++j) b[j] = *(const i32x4*)(bb + (size_t)j * 1024);
#pragma unroll
        for (int m = 0; m < 7; ++m)
#pragma unroll
            for (int j = 0; j < 4; ++j)
                acc[m][j] = __builtin_amdgcn_mfma_i32_16x16x64_i8(a[m], b[j], acc[m][j], 0, 0, 0);
        if (s < 17) {   // write next-step B into the other buffer
            signed char* dst = lds + A_BYTES + ((s + 1) & 1) * B_STEP + tid * 16;
            *(i32x4*)(dst) = nb0;
            *(i32x4*)(dst + 4096) = nb1;
        }
        __syncthreads();
    }

    // ---- epilogue: acc + 2*bias -> scale -> rint -> clamp -> int32 store ----
    float sc[4];
    int b2[4];
    const int coutbase = cb * 128 + chalf * 64;
#pragma unroll
    for (int j = 0; j < 4; ++j) {
        int cout = coutbase + j * 16 + row;
        sc[j] = wscale[cout] * 0.5f;          // 0.05/0.1 * ws
        b2[j] = 2 * bias[cout];
    }
    const int pixbase = rb * 224 + pxhalf * 112;
#pragma unroll
    for (int m = 0; m < 7; ++m) {
        int pl = pixbase + m * 16 + grp * 4;  // pixel of reg 0
        size_t obase = (size_t)n * (COUT * PIX_PER_IMG) + pl;
#pragma unroll
        for (int j = 0; j < 4; ++j) {
            int cout = coutbase + j * 16 + row;
            i32x4 v;
#pragma unroll
            for (int r = 0; r < 4; ++r) {
                int o = acc[m][j][r] + b2[j];
                float f = fmaf((float)o, sc[j], 5.0f);
                f = rintf(f);                 // RNE == jnp.round
                f = fminf(fmaxf(f, -128.0f), 127.0f);
                v[r] = (int)f;
            }
            *(i32x4*)(out + obase + (size_t)cout * PIX_PER_IMG) = v;
        }
    }
}

extern "C" void kernel_launch(void* const* d_in, const int* in_sizes, int n_in,
                              void* d_out, int out_size, void* d_ws, size_t ws_size,
                              hipStream_t stream) {
    const int* x = (const int*)d_in[0];
    const int* w = (const int*)d_in[1];
    const int* bias = (const int*)d_in[2];
    const float* ws = (const float*)d_in[3];
    int* out = (int*)d_out;

    signed char* xq = (signed char*)d_ws;                 // padded NHWC int8
    signed char* wq = xq + XQ_PAD_BYTES;                  // 288 KB fragment-ordered weights

    halo_kernel<<<NB_N, 256, 0, stream>>>(xq);            // 0.93 MB of 0xFD halos
    pack_x_kernel<<<NB_N * HH, 256, 0, stream>>>(x, xq);
    pack_w_kernel<<<72, 256, 0, stream>>>(w, wq);
    conv_kernel<<<896, 256, 0, stream>>>(xq, wq, bias, ws, out);
}

// Round 8
// 69.775 us; speedup vs baseline: 1.8316x; 1.1772x over previous
//
#include <hip/hip_runtime.h>

// QuantizedConv2d: N=32, CIN=128, H=W=56, COUT=256, 3x3, pad=1 (zp=-3), stride 1.
// Round 7: BARRIER-FREE K-loop. B (288KB, fragment-ordered, L2-resident) is
// loaded global->reg with 1-step prefetch instead of LDS double-buffering ->
// the 18 per-step __syncthreads disappear (exactly ONE barrier per block).
// A stays LDS-staged (6 padded rows, XOR-swizzled, read-only after prologue).
// pack_x vectorized: int4 global loads + stride-132 LDS byte-transpose.

typedef __attribute__((ext_vector_type(4))) int i32x4;

#define NB_N 32
#define CIN 128
#define HH 56
#define WW 56
#define PH 58                              // padded H/W
#define COUT 256
#define PIX_PER_IMG (HH*WW)                // 3136
#define X_IMG_INTS (PIX_PER_IMG*CIN)
#define XP_ROW_BYTES (PH*CIN)              // 7424
#define XP_IMG_BYTES (PH*XP_ROW_BYTES)     // 430592
#define XQ_PAD_BYTES ((size_t)NB_N*XP_IMG_BYTES)
#define A_BYTES (6*XP_ROW_BYTES)           // 44544

// ---------------- halo: fill padded-image borders with zp (0xFD) ----------------
__global__ __launch_bounds__(256) void halo_kernel(signed char* __restrict__ xq) {
    const i32x4 pad = {(int)0xFDFDFDFD, (int)0xFDFDFDFD, (int)0xFDFDFDFD, (int)0xFDFDFDFD};
    signed char* img = xq + (size_t)blockIdx.x * XP_IMG_BYTES;
    // full rows 0 and 57: 7424 B each = 464 x 16B
    for (int t = threadIdx.x; t < 928; t += 256) {
        int r = (t < 464) ? 0 : 57;
        int off = ((t < 464) ? t : t - 464) * 16;
        *(i32x4*)(img + (size_t)r * XP_ROW_BYTES + off) = pad;
    }
    // side columns w=0,57 for rows 1..56: 112 pixels x 8 x 16B
    for (int t = threadIdx.x; t < 896; t += 256) {
        int px = t >> 3;
        int q = t & 7;
        int r = 1 + (px >> 1);
        int w = (px & 1) ? 57 : 0;
        *(i32x4*)(img + ((size_t)r * PH + w) * CIN + q * 16) = pad;
    }
}

// ---------------- pack_x: NCHW int32 -> padded NHWC int8 (vectorized) ----------------
#define TS 132   // LDS tile stride (bytes) per w-row: 128 + 4 pad -> conflict-free
__global__ __launch_bounds__(256) void pack_x_kernel(const int* __restrict__ x,
                                                     signed char* __restrict__ xq) {
    __shared__ signed char tile[WW * TS];    // 7392 B, [w][c] stride 132
    int nh = blockIdx.x;                     // 0..N*H-1
    int n = nh / HH, h = nh - n * HH;
    const int* src = x + (size_t)n * X_IMG_INTS + h * WW;  // (n, c, h, 0)
    // Phase 1: 1792 int4 loads (c = idx/14, w0 = (idx%14)*4), byte-transpose into tile.
    for (int i = 0; i < 7; ++i) {
        int idx = i * 256 + threadIdx.x;
        int c = idx / 14;
        int q = idx - c * 14;
        i32x4 v = *(const i32x4*)(src + c * PIX_PER_IMG + q * 4);
#pragma unroll
        for (int k = 0; k < 4; ++k)
            tile[(q * 4 + k) * TS + c] = (signed char)v[k];
    }
    __syncthreads();
    // Phase 2: 1792 int reads (w = t/32, c4 = t%32), coalesced int stores.
    int* dst = (int*)(xq + (size_t)n * XP_IMG_BYTES + ((size_t)(h + 1) * PH + 1) * CIN);
    for (int i = 0; i < 7; ++i) {
        int t = i * 256 + threadIdx.x;
        int w = t >> 5, c4 = t & 31;
        dst[w * 32 + c4] = *(const int*)(tile + w * TS + c4 * 4);
    }
}

// ---------------- pack_w: OIHW int32 -> fragment-ordered int8 ----------------
// frag f = (tap*2 + kb)*16 + nfrag; byte = f*1024 + lane*16 + j
// -> weight[cout = nf*16 + (lane&15)][cin = kb*64 + (lane>>4)*16 + j][kh][kw]
__global__ __launch_bounds__(256) void pack_w_kernel(const int* __restrict__ w,
                                                     signed char* __restrict__ wq) {
    int idx = blockIdx.x * 256 + threadIdx.x;    // 0..18431
    if (idx >= 9 * 2 * 16 * 64) return;
    int lane = idx & 63;
    int fid = idx >> 6;
    int t = fid / 32;
    int rem = fid - t * 32;
    int kb = rem >> 4;
    int nf = rem & 15;
    int cout = nf * 16 + (lane & 15);
    int cinb = kb * 64 + (lane >> 4) * 16;
    int kh = t / 3, kw = t - kh * 3;
    union { signed char b[16]; i32x4 v; } u;
#pragma unroll
    for (int j = 0; j < 16; ++j) {
        int cin = cinb + j;
        u.b[j] = (signed char)w[((cout * CIN + cin) * 3 + kh) * 3 + kw];
    }
    *(i32x4*)(wq + (size_t)idx * 16) = u.v;
}

// ---------------- conv: LDS-A + global-reg-B implicit GEMM, ONE barrier ----------------
// grid = 896 blocks: img n (32) x rowblk rb (14, 4 rows each) x coutblk cb (2).
// wave (pxhalf, chalf): 112 px (7 m-frags) x 64 couts (4 n-frags); acc[7][4].
__global__ __launch_bounds__(256, 2) void conv_kernel(const signed char* __restrict__ xq,
                                                      const signed char* __restrict__ wq,
                                                      const int* __restrict__ bias,
                                                      const float* __restrict__ wscale,
                                                      int* __restrict__ out) {
    __shared__ __align__(16) signed char lds[A_BYTES];
    const int tid = threadIdx.x;
    const int lane = tid & 63, wv = tid >> 6;
    const int row = lane & 15, grp = lane >> 4;

    // XCD-chunked swizzle: 896 = 8*112; consecutive 112 blocks (4 images) per XCD.
    int orig = (blockIdx.x & 7) * 112 + (blockIdx.x >> 3);
    int n = orig / 28;
    int rr = orig - n * 28;
    int rb = rr >> 1;          // row-block: output rows [rb*4, rb*4+4)
    int cb = rr & 1;           // cout half: [cb*128, +128)
    int pxhalf = wv >> 1, chalf = wv & 1;

    const signed char* ximg = xq + (size_t)n * XP_IMG_BYTES + (size_t)rb * 4 * XP_ROW_BYTES;

    // ---- prologue: A-halo (6 padded rows) into LDS, swizzled ----
    // LDS[d] = global[g],  g = d ^ (((d>>7)&7)<<4)   (involution on bits 4-6)
#pragma unroll
    for (int k = 0; k < 11; ++k) {
        int d = k * 4096 + tid * 16;
        if (d < A_BYTES) {
            int g = d ^ (((d >> 7) & 7) << 4);
            i32x4 v = *(const i32x4*)(ximg + g);
            *(i32x4*)(lds + d) = v;
        }
    }
    __syncthreads();   // the ONLY barrier

    // per-m center pixel index in halo (padded coords, rows 0..5 of halo)
    int pc[7];
#pragma unroll
    for (int m = 0; m < 7; ++m) {
        int off = pxhalf * 112 + m * 16 + row;               // 0..223
        int lr = (off >= 56) + (off >= 112) + (off >= 168);  // off/56
        int w = off - lr * 56;
        pc[m] = (lr + 1) * PH + (w + 1);
    }

    const int tapd[9] = {-PH - 1, -PH, -PH + 1, -1, 0, 1, PH - 1, PH, PH + 1};

    // B direct from global (fragment-ordered, L2-resident), 1-step prefetch.
    const signed char* wbase = wq + (size_t)(cb * 8 + chalf * 4) * 1024 + lane * 16;

    i32x4 acc[7][4] = {};
    i32x4 bn[4];
#pragma unroll
    for (int j = 0; j < 4; ++j) bn[j] = *(const i32x4*)(wbase + j * 1024);

#pragma unroll
    for (int s = 0; s < 18; ++s) {
        const int t = s >> 1, kb = s & 1;
        i32x4 b[4];
#pragma unroll
        for (int j = 0; j < 4; ++j) b[j] = bn[j];
        if (s < 17) {   // prefetch next step's B fragments (hidden under 28 MFMAs)
#pragma unroll
            for (int j = 0; j < 4; ++j)
                bn[j] = *(const i32x4*)(wbase + (s + 1) * 16384 + j * 1024);
        }
        // A ds_reads (swizzled)
        i32x4 a[7];
#pragma unroll
        for (int m = 0; m < 7; ++m) {
            int pix = pc[m] + tapd[t];
            int g = (pix << 7) + (kb << 6) + (grp << 4);
            int d = g ^ ((pix & 7) << 4);
            a[m] = *(const i32x4*)(lds + d);
        }
#pragma unroll
        for (int m = 0; m < 7; ++m)
#pragma unroll
            for (int j = 0; j < 4; ++j)
                acc[m][j] = __builtin_amdgcn_mfma_i32_16x16x64_i8(a[m], b[j], acc[m][j], 0, 0, 0);
    }

    // ---- epilogue: acc + 2*bias -> scale -> rint -> clamp -> int32 store ----
    float sc[4];
    int b2[4];
    const int coutbase = cb * 128 + chalf * 64;
#pragma unroll
    for (int j = 0; j < 4; ++j) {
        int cout = coutbase + j * 16 + row;
        sc[j] = wscale[cout] * 0.5f;          // 0.05/0.1 * ws
        b2[j] = 2 * bias[cout];
    }
    const int pixbase = rb * 224 + pxhalf * 112;
#pragma unroll
    for (int m = 0; m < 7; ++m) {
        int pl = pixbase + m * 16 + grp * 4;  // pixel of reg 0
        size_t obase = (size_t)n * (COUT * PIX_PER_IMG) + pl;
#pragma unroll
        for (int j = 0; j < 4; ++j) {
            int cout = coutbase + j * 16 + row;
            i32x4 v;
#pragma unroll
            for (int r = 0; r < 4; ++r) {
                int o = acc[m][j][r] + b2[j];
                float f = fmaf((float)o, sc[j], 5.0f);
                f = rintf(f);                 // RNE == jnp.round
                f = fminf(fmaxf(f, -128.0f), 127.0f);
                v[r] = (int)f;
            }
            *(i32x4*)(out + obase + (size_t)cout * PIX_PER_IMG) = v;
        }
    }
}

extern "C" void kernel_launch(void* const* d_in, const int* in_sizes, int n_in,
                              void* d_out, int out_size, void* d_ws, size_t ws_size,
                              hipStream_t stream) {
    const int* x = (const int*)d_in[0];
    const int* w = (const int*)d_in[1];
    const int* bias = (const int*)d_in[2];
    const float* ws = (const float*)d_in[3];
    int* out = (int*)d_out;

    signed char* xq = (signed char*)d_ws;                 // padded NHWC int8
    signed char* wq = xq + XQ_PAD_BYTES;                  // 288 KB fragment-ordered weights

    halo_kernel<<<NB_N, 256, 0, stream>>>(xq);            // 0.93 MB of 0xFD halos
    pack_x_kernel<<<NB_N * HH, 256, 0, stream>>>(x, xq);
    pack_w_kernel<<<72, 256, 0, stream>>>(w, wq);
    conv_kernel<<<896, 256, 0, stream>>>(xq, wq, bias, ws, out);
}